// Round 7
// baseline (72.063 us; speedup 1.0000x reference)
//
#include <hip/hip_runtime.h>

// out[b,m,n,p] = s[b,m] * p1[b,n] * q[m,p]
//   s[b,m]  = sum_i x[b,i]*w[m,i,0]
//   p1[b,n] = sum_i x[b,i]*w[n,i,1]
//   q[m,p]  = sum_i x[m,i]*w[p,i,2]   (second matmul broadcasts over m, not b)
// Main kernel is a fill-style grid-stride sweep: all resident waves write in a
// compact window marching linearly through the 340 MB output (DRAM-row-friendly),
// instead of ~2k private per-block streams.

#define NB 96
#define TBL (NB * NB)              // 9216
#define TOT4 (TBL * TBL / 4)       // 21,233,664 f32x4 elements
#define NBLK 2048                  // 8 blocks/CU exactly
#define NTHR (NBLK * 256)          // 524,288 threads
#define NIT ((TOT4 + NTHR - 1) / NTHR)   // 41

typedef float f32x4 __attribute__((ext_vector_type(4)));

__global__ __launch_bounds__(256) void prep_kernel(
    const float* __restrict__ x,   // [96,3]
    const float* __restrict__ w,   // [96,3,8]  w[o,i,j] at o*24+i*8+j
    float* __restrict__ ws)        // [3*9216]: s | p1 | q
{
    const int v = blockIdx.x * 256 + threadIdx.x;
    if (v >= 3 * TBL) return;
    const int which = v / TBL;     // 0=s, 1=p1, 2=q
    const int r     = v % TBL;
    const int a     = r / NB;
    const int c     = r % NB;
    const float x0 = x[a*3 + 0], x1 = x[a*3 + 1], x2 = x[a*3 + 2];
    ws[v] = x0 * w[c*24 + which] + x1 * w[c*24 + 8 + which] + x2 * w[c*24 + 16 + which];
}

__global__ __launch_bounds__(256) void nckart_sweep(
    const float* __restrict__ ws,  // s | p1 | q
    float* __restrict__ out)       // [96,96,96,96]
{
    const int t = blockIdx.x * 256 + threadIdx.x;

    const float* s  = ws;
    const float* p1 = ws + TBL;
    const f32x4* q4 = reinterpret_cast<const f32x4*>(ws + 2 * TBL);
    f32x4* o4 = reinterpret_cast<f32x4*>(out);

    #pragma unroll
    for (int it = 0; it < NIT; ++it) {
        const unsigned idx = (unsigned)t + (unsigned)it * NTHR;
        if (idx < TOT4) {
            const unsigned row = idx / 24u;          // bm*96 + n, magic div
            const unsigned p4  = idx - row * 24u;
            const unsigned bm  = row / 96u;
            const unsigned n   = row - bm * 96u;
            const unsigned b   = bm / 96u;
            const unsigned m   = bm - b * 96u;
            f32x4 v = q4[m * 24u + p4];
            v *= s[bm] * p1[b * 96u + n];
            o4[idx] = v;
        }
    }
}

extern "C" void kernel_launch(void* const* d_in, const int* in_sizes, int n_in,
                              void* d_out, int out_size, void* d_ws, size_t ws_size,
                              hipStream_t stream) {
    const float* x = (const float*)d_in[0];
    const float* w = (const float*)d_in[1];
    float* out = (float*)d_out;
    float* ws  = (float*)d_ws;

    prep_kernel<<<(3 * TBL + 255) / 256, 256, 0, stream>>>(x, w, ws);
    nckart_sweep<<<NBLK, 256, 0, stream>>>(ws, out);
}